// Round 11
// baseline (45.135 us; speedup 1.0000x reference)
//
#include <hip/hip_runtime.h>

// EqFrePBC: frequency-domain perturbation compensation. 2-node graph, no serial stage.
// Measured on MI355X: intra-kernel grid sync >=13us (cg / fence-spin / sc1-flag all
// worse); kernel boundary ~free; node-count 2 vs 3 neutral; bodies ~5us of ~23us.
// This round removes the serial 4-block IFFT kernel: each K1 block turns its own
// 64-bin dfreq tile into time domain via partial DFT (per-t twiddle recurrence)
// and atomically accumulates into out, which K0 pre-fills with the cropped input.
// B=2, L=2048, N=2 modes, pairs = full 40x40 grid (n1,n2 in [-20,19]).
//   G[b,m,d]    = sum_n xf[b,m,n]*conj(xf[b,(m-(d-20))%L,n])
//   S2[b,d,l]   = sum_{n1i} w[n1i,d] * G[b,(l-(n1i-20))%L,d]
//   dfreq[b,n,l]= sum_d S2[b,d,l] * xf[b,n,(l-(d-20))%L]
//   out[b,t,n]  = x[b,t,n] + (P_b/L) * sum_l dfreq[b,n,l] e^{+2pi i l t/L},  t in [20,2028)
// Bias is constant over freq -> IFFT puts it only at t=0, cropped out.
// K0 (16 blk x 512): out = cropped x (ordering vs K1 atomics via kernel boundary).
// K1 (64 blk x 512): dual-mode in-LDS fwd FFT + all-40-d S2 + deltaf tile
//   + partial-DFT scatter into out via unsafeAtomicAdd. No workspace used.

#define L_FFT 2048
#define NB 2
#define NM 2
#define ND 40
#define CROP 20
#define LOUT 2008
#define NT 512
#define TILE 64        // l-tile width per K1 block
#define NGRP 8         // d-groups per block (64 lanes each)
#define GHALO 103      // TILE + 39 G entries per (group, iteration)
#define ANGC 3.0679615757712823e-03f   // 2*pi/2048

__device__ __forceinline__ float2 cmul(float2 a, float2 b) {
    return make_float2(a.x*b.x - a.y*b.y, a.x*b.y + a.y*b.x);
}
__device__ __forceinline__ float2 cmulc(float2 a, float2 b) {  // a * conj(b)
    return make_float2(a.x*b.x + a.y*b.y, a.y*b.x - a.x*b.y);
}

// One radix-4 Stockham butterfly (inputs strided 512, outputs at 4jm+k2+{0,m,2m,3m}).
template<int SIGN>
__device__ __forceinline__ void r4_bfly(const float2* src, float2* dst, int tid,
                                        int m, float2 w1, float2 w2, float2 w3) {
    int k2 = tid & (m - 1);
    int jm = tid - k2;
    float2 A = src[tid];
    float2 C = src[tid + 512];
    float2 B = src[tid + 1024];
    float2 D = src[tid + 1536];
    float2 T0 = make_float2(A.x + B.x, A.y + B.y);
    float2 T1 = make_float2(A.x - B.x, A.y - B.y);
    float2 T2 = make_float2(C.x + D.x, C.y + D.y);
    float2 cd = make_float2(C.x - D.x, C.y - D.y);
    float2 T3 = (SIGN < 0) ? make_float2(cd.y, -cd.x)    // -i*(C-D)
                           : make_float2(-cd.y, cd.x);   // +i*(C-D)
    int base = 4 * jm + k2;
    dst[base]       = make_float2(T0.x + T2.x, T0.y + T2.y);
    dst[base + m]   = cmul(make_float2(T1.x + T3.x, T1.y + T3.y), w1);
    dst[base + 2*m] = cmul(make_float2(T0.x - T2.x, T0.y - T2.y), w2);
    dst[base + 3*m] = cmul(make_float2(T1.x - T3.x, T1.y - T3.y), w3);
}

// Dual-mode radix-4 Stockham FFT, 2048 pts, 512 threads: both modes' butterflies
// between the same barriers (6 barrier stages). Results land back in x0 / x1.
template<int SIGN>
__device__ void fft2048_r4_dual(float2* x0, float2* t0, float2* x1, float2* t1, int tid) {
    float2 *s0 = x0, *d0 = t0, *s1 = x1, *d1 = t1;
    #pragma unroll
    for (int m = 1; m <= 256; m *= 4) {
        __syncthreads();
        int jm = tid - (tid & (m - 1));
        float ang = (float)(SIGN * jm) * ANGC;
        float sv = __sinf(ang), cv = __cosf(ang);
        float2 w1 = make_float2(cv, sv);
        float2 w2 = cmul(w1, w1);
        float2 w3 = cmul(w2, w1);
        r4_bfly<SIGN>(s0, d0, tid, m, w1, w2, w3);
        r4_bfly<SIGN>(s1, d1, tid, m, w1, w2, w3);
        float2* t;
        t = s0; s0 = d0; d0 = t;
        t = s1; s1 = d1; d1 = t;
    }
    __syncthreads();
    // final radix-2 stage, m=1024 (twiddle 1): src = t-buffers, dst = x-buffers
    #pragma unroll
    for (int it = 0; it < 2; ++it) {
        int q = tid + it * 512;
        float2 a0 = s0[q], b0 = s0[q + 1024];
        d0[q]        = make_float2(a0.x + b0.x, a0.y + b0.y);
        d0[q + 1024] = make_float2(a0.x - b0.x, a0.y - b0.y);
        float2 a1 = s1[q], b1 = s1[q + 1024];
        d1[q]        = make_float2(a1.x + b1.x, a1.y + b1.y);
        d1[q + 1024] = make_float2(a1.x - b1.x, a1.y - b1.y);
    }
    __syncthreads();
}

// K0: out = cropped input (stack of real/imag). 16 blk x 512; pair p covers
// [b][t_out][n]; out[p*2+{0,1}] = x[b, t_out+20, n].{re,im}
__global__ __launch_bounds__(NT) void out_init_kernel(const float* __restrict__ xr,
                                                      const float* __restrict__ xi,
                                                      float* __restrict__ out) {
    int p = blockIdx.x * NT + threadIdx.x;
    if (p >= NB * LOUT * NM) return;
    int n  = p & 1;
    int to = (p >> 1) % LOUT;
    int b  = p / (LOUT * NM);
    int gi = (b * L_FFT + to + CROP) * NM + n;
    out[p * 2]     = xr[gi];
    out[p * 2 + 1] = xi[gi];
}

// K1: dual-mode FFT + all-d S2 + deltaf tile + partial-DFT atomic scatter.
// One block per (b, l-tile of 64).
__global__ __launch_bounds__(NT, 2) void gs2_kernel(const float* __restrict__ xr,
                                                    const float* __restrict__ xi,
                                                    const float* __restrict__ wr,
                                                    const float* __restrict__ wi,
                                                    const float* __restrict__ task,
                                                    float* __restrict__ out) {
    __shared__ float2 xs0[L_FFT];          // mode-0 spectrum
    __shared__ float2 xs1[L_FFT];          // mode-1 spectrum
    __shared__ float2 scr0[L_FFT];         // ping-pong m0; then Gs, then dtile
    __shared__ float2 scr1[L_FFT];         // ping-pong m1; then pr0/pr1 (64 KB total)

    int blk = blockIdx.x;
    int b   = blk >> 5;            // 32 tiles per batch
    int l0  = (blk & 31) * TILE;
    int tid = threadIdx.x;

    // x[b,t,n] at (b*2048+t)*2+n: modes adjacent -> float2 loads give both.
    const float2* xr2 = (const float2*)xr;
    const float2* xi2 = (const float2*)xi;
    for (int t = tid; t < L_FFT; t += NT) {
        float2 re = xr2[b * L_FFT + t];
        float2 im = xi2[b * L_FFT + t];
        xs0[t] = make_float2(re.x, im.x);
        xs1[t] = make_float2(re.y, im.y);
    }

    fft2048_r4_dual<-1>(xs0, scr0, xs1, scr1, tid);   // spectra -> xs0, xs1

    // scr re-purposed
    float2* Gs    = scr0;                  // NGRP*GHALO = 824
    float2* pr0   = scr1;                  // 512
    float2* pr1   = scr1 + NT;             // 512
    float2* dtile = scr0;                  // [2][64] after Gs is dead

    int grp = tid >> 6;            // d-group 0..7 (wave-uniform)
    int lt  = tid & 63;            // l within tile
    int l   = l0 + lt;
    float2 acc0 = make_float2(0.f, 0.f);
    float2 acc1 = make_float2(0.f, 0.f);

    #pragma unroll 1
    for (int it = 0; it < 5; ++it) {
        int d  = it * NGRP + grp;  // wave-uniform
        int dd = d - 20;
        __syncthreads();           // protect Gs from previous iteration's readers
        #pragma unroll
        for (int p = 0; p < 2; ++p) {
            int j = lt + p * 64;
            if (j < GHALO) {
                int m = l0 - 19 + j;
                float2 g0 = cmulc(xs0[m & (L_FFT-1)], xs0[(m - dd) & (L_FFT-1)]);
                float2 g1 = cmulc(xs1[m & (L_FFT-1)], xs1[(m - dd) & (L_FFT-1)]);
                Gs[grp * GHALO + j] = make_float2(g0.x + g1.x, g0.y + g1.y);
            }
        }
        __syncthreads();
        // S2[l] = sum_{n1i} w[n1i,d] * Gs[grp][lt + 39 - n1i]; w loads wave-uniform.
        float2 s2 = make_float2(0.f, 0.f);
        #pragma unroll 4
        for (int n1i = 0; n1i < ND; ++n1i) {
            float2 g = Gs[grp * GHALO + lt + 39 - n1i];
            float wxr = wr[n1i * ND + d], wxi = wi[n1i * ND + d];
            s2.x += wxr * g.x - wxi * g.y;
            s2.y += wxr * g.y + wxi * g.x;
        }
        float2 xv0 = xs0[(l - dd) & (L_FFT-1)];
        float2 xv1 = xs1[(l - dd) & (L_FFT-1)];
        float2 c0 = cmul(s2, xv0);
        float2 c1 = cmul(s2, xv1);
        acc0.x += c0.x; acc0.y += c0.y;
        acc1.x += c1.x; acc1.y += c1.y;
    }
    // cross-group reduction -> scaled dfreq tile in LDS
    __syncthreads();               // Gs readers done
    pr0[tid] = acc0;
    pr1[tid] = acc1;
    __syncthreads();
    if (tid < 128) {
        int n = tid >> 6, lq = tid & 63;
        float2* pr = n ? pr1 : pr0;
        float2 s = make_float2(0.f, 0.f);
        #pragma unroll
        for (int g = 0; g < NGRP; ++g) {
            float2 v = pr[g * 64 + lq];
            s.x += v.x; s.y += v.y;
        }
        float P = 1e-3f * __powf(10.f, task[b * 4] * 0.1f) * 0.5f;   // /N with N=2
        float scale = P * (1.0f / (float)L_FFT);                     // fold ifft 1/L
        dtile[n * TILE + lq] = make_float2(s.x * scale, s.y * scale);
    }
    __syncthreads();

    // Partial DFT: delta(t) += sum_{j=0..63} dtile[n][j] * e^{+2pi i (l0+j) t / L}
    // Per t: start twiddle via exact (l0*t mod 2048), advance ratio e^{+2pi i t/L}.
    #pragma unroll 1
    for (int it = 0; it < 4; ++it) {
        int t = tid + it * NT;
        if (t < CROP || t >= L_FFT - CROP) continue;
        float angr = (float)t * ANGC;
        float2 r = make_float2(__cosf(angr), __sinf(angr));
        int a0i = (int)(((long long)l0 * t) & (L_FFT - 1));
        float ang0 = (float)a0i * ANGC;
        float2 w = make_float2(__cosf(ang0), __sinf(ang0));
        float2 s0 = make_float2(0.f, 0.f);
        float2 s1 = make_float2(0.f, 0.f);
        #pragma unroll 4
        for (int j = 0; j < TILE; ++j) {
            float2 d0 = dtile[j];            // broadcast reads
            float2 d1 = dtile[TILE + j];
            s0.x += d0.x * w.x - d0.y * w.y;
            s0.y += d0.x * w.y + d0.y * w.x;
            s1.x += d1.x * w.x - d1.y * w.y;
            s1.y += d1.x * w.y + d1.y * w.x;
            w = cmul(w, r);
        }
        int oi = (b * LOUT + (t - CROP)) * NM * 2;
        unsafeAtomicAdd(&out[oi],     s0.x);
        unsafeAtomicAdd(&out[oi + 1], s0.y);
        unsafeAtomicAdd(&out[oi + 2], s1.x);
        unsafeAtomicAdd(&out[oi + 3], s1.y);
    }
}

extern "C" void kernel_launch(void* const* d_in, const int* in_sizes, int n_in,
                              void* d_out, int out_size, void* d_ws, size_t ws_size,
                              hipStream_t stream) {
    const float* xr   = (const float*)d_in[0];
    const float* xi   = (const float*)d_in[1];
    const float* task = (const float*)d_in[2];
    const float* wr   = (const float*)d_in[3];
    const float* wi   = (const float*)d_in[4];
    // d_in[5], d_in[6]: fc_br / fc_bi -- bias lands only at t=0 after IFFT, cropped out.
    float* out = (float*)d_out;

    hipLaunchKernelGGL(out_init_kernel, dim3((NB * LOUT * NM + NT - 1) / NT), dim3(NT),
                       0, stream, xr, xi, out);
    hipLaunchKernelGGL(gs2_kernel, dim3(64), dim3(NT), 0, stream,
                       xr, xi, wr, wi, task, out);
}